// Round 1
// baseline (178.495 us; speedup 1.0000x reference)
//
#include <hip/hip_runtime.h>
#include <math.h>

// Problem constants
#define KC 1024       // num codes
#define DD 256        // embedding dim
#define NROWS 32768   // 32 * 32 * 32 (B*H*W)
#define NELEM 8388608 // NROWS * DD

typedef _Float16 f16;
typedef __attribute__((ext_vector_type(8))) _Float16 f16x8;
typedef __attribute__((ext_vector_type(16))) float f32x16;

#define KEY_SCALE 2097152.0f   // 2^21; |score| <= ~0.63 -> |ikey| < 2^21
#define KEY_INV   (1.0f / 2097152.0f)

// ---------------------------------------------------------------------------
// prep: zero counts/loss64/done + c_sq (exact fp32) + emb -> fp16 swizzled
// grid 256 x 256.  emb_h layout: [kg 32][code 1024][8]
// ---------------------------------------------------------------------------
__global__ void vq_prep_kernel(const float* __restrict__ emb, f16* __restrict__ emb_h,
                               float* __restrict__ c_sq, int* __restrict__ counts,
                               float* __restrict__ loss64, unsigned* __restrict__ done) {
    const int tid = threadIdx.x;
    const int gt = blockIdx.x * 256 + tid;
    if (gt < KC) counts[gt] = 0;
    if (gt < 64) loss64[gt] = 0.0f;
    if (gt == 0) *done = 0u;
    {
        int k = blockIdx.x * 4 + (tid >> 6);
        int lane = tid & 63;
        float4 v = *(const float4*)(emb + (size_t)k * DD + lane * 4);
        float s = v.x * v.x + v.y * v.y + v.z * v.z + v.w * v.w;
        #pragma unroll
        for (int off = 32; off > 0; off >>= 1) s += __shfl_down(s, off);
        if (lane == 0) c_sq[k] = s;
    }
    if (gt < 32768) {
        int code = gt & 1023;
        int kg = gt >> 10;
        const float* p = emb + (size_t)code * DD + kg * 8;
        float4 v0 = *(const float4*)p;
        float4 v1 = *(const float4*)(p + 4);
        f16x8 hcv;
        hcv[0] = (f16)v0.x; hcv[1] = (f16)v0.y; hcv[2] = (f16)v0.z; hcv[3] = (f16)v0.w;
        hcv[4] = (f16)v1.x; hcv[5] = (f16)v1.y; hcv[6] = (f16)v1.z; hcv[7] = (f16)v1.w;
        *(f16x8*)(emb_h + (size_t)gt * 8) = hcv;
    }
}

// ---------------------------------------------------------------------------
// Fused main, re-tiled for occupancy/stagger:
//   32 rows/block, 512 threads (8 waves), grid 1024 -> 4 blocks/CU resident.
//   Wave w owns codes [w*128,(w+1)*128) as 4 chunks of 32; ONE 32x32 acc
//   per chunk (16 AGPR) + bk[16] running argmin keys -> ~half the register
//   state of the 64-row tiling, targeting >=6 waves/SIMD (24-32 waves/CU).
//   counts/loss atomics are DEFERRED to after the out-writes so no barrier
//   drains a contended atomic; block losses spread over 64 slots.
// argmin key = trunc(score*2^21)*1024 + code  (monotone, first-min ties).
// loss per row: sum_c (q-z)^2 = score_min + ||z||^2.
// ---------------------------------------------------------------------------
__global__ __launch_bounds__(512, 6)
void vq_main_kernel(const float* __restrict__ z, const float* __restrict__ emb,
                    const f16* __restrict__ emb_h, const float* __restrict__ c_sq,
                    int* __restrict__ counts, float* __restrict__ loss64,
                    unsigned* __restrict__ done, float* __restrict__ out,
                    float* __restrict__ out_tail) {
    __shared__ __align__(16) char smem_raw[33280]; // z_s (A/B) then Qh (C)
    __shared__ int   bl_key[8][32];
    __shared__ float zsq_part[16][32];
    __shared__ int   idx_s[32];
    __shared__ float wsum[8];
    __shared__ int   last_flag;

    f16* z_s = (f16*)smem_raw;      // [kg 32][row 32][8]  = 16384 B
    float* Qh = (float*)smem_raw;   // [row 32][260]       = 33280 B

    const int tid = threadIdx.x;
    const int n0 = blockIdx.x * 32;
    const int b = n0 >> 10;
    const int hw0 = n0 & 1023;

    // ---- Phase A: stage z tile fp16 + per-row ||z||^2 partials ----
    {
        const int r = tid & 31;
        const int kq = tid >> 5;   // 0..15, each covers 16 channels
        const float* zp = z + (size_t)b * (DD * 1024) + hw0 + r;
        float sq = 0.f;
        #pragma unroll
        for (int it = 0; it < 2; ++it) {
            int kg = kq * 2 + it;
            f16x8 hv;
            #pragma unroll
            for (int j = 0; j < 8; ++j) {
                float v = zp[(size_t)(kg * 8 + j) * 1024];
                sq += v * v;
                hv[j] = (f16)v;
            }
            *(f16x8*)&z_s[(kg * 32 + r) * 8] = hv;
        }
        zsq_part[kq][r] = sq;
    }
    __syncthreads();

    const int m = tid & 31;        // code-lane within 32-tile
    const int h = (tid >> 5) & 1;  // k-half
    const int w = tid >> 6;        // wave id 0..7

    int bk[16];
    #pragma unroll
    for (int s = 0; s < 16; ++s) bk[s] = 0x7FFFFFFF;

    // ---- Phase B: MFMA + running packed argmin ----
    for (int c = 0; c < 4; ++c) {
        const int code = w * 128 + c * 32 + m;
        const f16* ebp = emb_h + (size_t)h * 8192 + (size_t)code * 8;

        f32x16 acc;
        #pragma unroll
        for (int i = 0; i < 16; ++i) acc[i] = 0.f;

        #pragma unroll 4
        for (int ks = 0; ks < 16; ++ks) {
            f16x8 a0 = *(const f16x8*)(z_s + ((2 * ks + h) * 32 + m) * 8);
            f16x8 b0 = *(const f16x8*)(ebp + (size_t)ks * 16384);
            acc = __builtin_amdgcn_mfma_f32_32x32x16_f16(a0, b0, acc, 0, 0, 0);
        }

        const float cs = c_sq[code];
        #pragma unroll
        for (int reg = 0; reg < 16; ++reg) {
            float s0 = fmaf(-2.f, acc[reg], cs);
            int k0 = (int)(s0 * KEY_SCALE) * 1024 + code;
            bk[reg] = min(bk[reg], k0);
        }
    }

    // butterfly min across the 32 lanes of each k-half (rows stay distinct)
    #pragma unroll
    for (int s = 0; s < 16; ++s) {
        int k = bk[s];
        #pragma unroll
        for (int d = 16; d >= 1; d >>= 1) k = min(k, __shfl_xor(k, d));
        bk[s] = k;
    }
    if (m == 0) {
        #pragma unroll
        for (int s = 0; s < 16; ++s) {
            int row = (s & 3) + 8 * (s >> 2) + 4 * h;
            bl_key[w][row] = bk[s];
        }
    }
    __syncthreads();

    // combine 8 waves -> idx + per-block loss (atomics deferred to post-write)
    int my_idx = 0;
    float block_loss = 0.f;
    if (tid < 32) {
        int k = bl_key[0][tid];
        #pragma unroll
        for (int w2 = 1; w2 < 8; ++w2) k = min(k, bl_key[w2][tid]);
        my_idx = k & 1023;              // low 10 bits = code (two's complement safe)
        idx_s[tid] = my_idx;
        float zq = 0.f;
        #pragma unroll
        for (int p = 0; p < 16; ++p) zq += zsq_part[p][tid];
        float lr = (float)(k >> 10) * KEY_INV + zq;  // score_min + ||z||^2
        #pragma unroll
        for (int off = 16; off > 0; off >>= 1) lr += __shfl_down(lr, off);
        block_loss = lr;                // lane 0 valid
    }
    __syncthreads();

    // ---- Phase C1: Qh[r][c] = emb[idx[r]][c] fp32, stride 260 ----
    {
        int r = tid & 31;
        int part = tid >> 5;  // 0..15 -> 16 channels each
        const float* ep = emb + (size_t)idx_s[r] * DD + part * 16;
        float* qrow = Qh + r * 260 + part * 16;
        #pragma unroll
        for (int g = 0; g < 4; ++g)
            *(float4*)(qrow + g * 4) = *(const float4*)(ep + g * 4);
    }
    __syncthreads();

    // ---- Phase C2: coalesced channel-major writes ----
    {
        int r = tid & 31;
        int part = tid >> 5;
        const float* qr = Qh + r * 260;
        const size_t base = (size_t)b * (DD * 1024) + hw0 + r;
        #pragma unroll
        for (int g = 0; g < 4; ++g) {
            int c0 = part * 16 + g * 4;
            float4 v = *(const float4*)(qr + c0);
            out[base + (size_t)c0 * 1024] = v.x;
            out[base + (size_t)(c0 + 1) * 1024] = v.y;
            out[base + (size_t)(c0 + 2) * 1024] = v.z;
            out[base + (size_t)(c0 + 3) * 1024] = v.w;
        }
    }

    // ---- deferred stats: no barrier waits on these before the writes ----
    if (tid < 32) atomicAdd(&counts[my_idx], 1);
    if (tid == 0) atomicAdd(&loss64[blockIdx.x & 63], block_loss);

    // ---- last-block finalize ----
    __syncthreads();
    if (tid == 0) {
        __threadfence();
        last_flag = (atomicAdd(done, 1u) == 1023u) ? 1 : 0;
    }
    __syncthreads();
    if (last_flag) {
        __threadfence();
        float s = 0.f;
        for (int k = tid; k < KC; k += 512) {
            int cnt = atomicAdd(&counts[k], 0);
            float pr = (float)cnt * (1.0f / (float)NROWS);
            s += pr * logf(pr + 1e-10f);
        }
        #pragma unroll
        for (int off = 32; off > 0; off >>= 1) s += __shfl_down(s, off);
        if ((tid & 63) == 0) wsum[tid >> 6] = s;
        float loss_tot = 0.f;
        if (tid < 64) {
            float lv = atomicAdd(&loss64[tid], 0.0f);
            #pragma unroll
            for (int off = 32; off > 0; off >>= 1) lv += __shfl_down(lv, off);
            loss_tot = lv;              // lane 0 (tid 0) valid
        }
        __syncthreads();
        if (tid == 0) {
            float ent = 0.f;
            #pragma unroll
            for (int p = 0; p < 8; ++p) ent += wsum[p];
            out_tail[0] = 1.25f * loss_tot * (1.0f / (float)NELEM);
            out_tail[1] = expf(-ent);
        }
    }
}

// ---------------------------------------------------------------------------
extern "C" void kernel_launch(void* const* d_in, const int* in_sizes, int n_in,
                              void* d_out, int out_size, void* d_ws, size_t ws_size,
                              hipStream_t stream) {
    const float* z = (const float*)d_in[0];    // (32,256,32,32)
    const float* emb = (const float*)d_in[1];  // (1024,256)
    float* out = (float*)d_out;                // 8388608 + 2

    char* wsb = (char*)d_ws;
    f16* emb_h = (f16*)wsb;                    // 524288 B
    float* c_sq = (float*)(wsb + 524288);      // 4096 B
    int* counts = (int*)(wsb + 528384);        // 4096 B
    float* loss64 = (float*)(wsb + 532480);    // 256 B
    unsigned* done = (unsigned*)(wsb + 532736);

    hipLaunchKernelGGL(vq_prep_kernel, dim3(256), dim3(256), 0, stream,
                       emb, emb_h, c_sq, counts, loss64, done);
    hipLaunchKernelGGL(vq_main_kernel, dim3(1024), dim3(512), 0, stream,
                       z, emb, emb_h, c_sq, counts, loss64, done, out, out + NELEM);
}